// Round 5
// baseline (317.708 us; speedup 1.0000x reference)
//
#include <hip/hip_runtime.h>
#include <hip/hip_bf16.h>

// ContextualConv2d as implicit GEMM on MFMA.
// GEMM view: M = N*H*W = 131072, N = C_OUT = 256, K = CIN*9 = 1152.
// Round 10: DELETE THE xP INTERMEDIATE. r5-r9: conv pinned at ~100 us across
//           four schedules while TOTAL is pinned at ~268 => ~170 us lives in
//           prep_all (xP transpose kernel) + overhead. Now conv reads x
//           directly: per block, a 4-row fp32 slab (131 KB, wave-coalesced
//           256 B rows) is converted in-register and ds_write_b128'd into a
//           STRIDE-17-CHUNK padded LDS layout (row stride 272 B, odd chunk
//           multiplier => bank-quad=(row+chunk)%8, conflict-free both sides,
//           no XOR swizzle). prep_x + zero_halo + 71 MB of xP round-trip
//           traffic are gone; prep is just prep_wc (~5 MB).
//           conv: 2-h-row blocks (1024 blocks), A-LDS 71.8 KB => 2 blocks/CU,
//           4 waves/SIMD (occupancy 19%->~50%), acc[4][4]=64 VGPR,
//           launch_bounds(512,4). K-loop = r9's verified barrier-free form
//           (resident A, B frags global->VGPR, depth-1 prefetch).

#define NN   32
#define CIN  128
#define HH   64
#define WW   64
#define COUT 256
#define CDIM 64

#define WT_BYTES  ((size_t)9*COUT*CIN*2)         //    589,824
#define CTX_BYTES ((size_t)NN*COUT*4)            //     32,768
#define WS_NEEDED (WT_BYTES + CTX_BYTES)

// LDS A layout: 264 rows (4 padded h x 66 padded w) x 17 chunks of 16B
// (16 data chunks = 128 ci bf16, +1 pad chunk). shorts: row*136 + chunk*8.
#define AROWS 264
#define ARSTR 136                                 // shorts per row (272 B)
#define ACHNK 4488                                // total 16B chunks (264*17)

typedef __attribute__((ext_vector_type(8))) short short8;   // 8 bf16 = 4 VGPRs
typedef __attribute__((ext_vector_type(4))) float float4v;

#define SETPRIO(x) __builtin_amdgcn_s_setprio(x)

// ---------------- prep_wc: weight transpose + ctx GEMM --------------------------
// blocks 0..1151:  wT[tap][co][ci] = bf16(wgt[co][ci][tap])
// blocks 1152..1183: ctx[n][co] = bias[co] + sum_d c[n,d]*cw[co,d]
__global__ __launch_bounds__(256) void prep_wc(const float* __restrict__ wgt,
                                               const float* __restrict__ c,
                                               const float* __restrict__ cw,
                                               const float* __restrict__ bias,
                                               __hip_bfloat16* __restrict__ wT,
                                               float* __restrict__ ctx) {
    int bid = blockIdx.x;
    if (bid < 1152) {
        int idx = bid * 256 + threadIdx.x;       // 294912
        int ci  = idx & 127;
        int co  = (idx >> 7) & 255;
        int tap = idx >> 15;
        wT[idx] = __float2bfloat16(wgt[((size_t)co * CIN + ci) * 9 + tap]);
    } else {
        int idx = (bid - 1152) * 256 + threadIdx.x;   // 8192
        int co = idx & 255, n = idx >> 8;
        float a = bias[co];
        #pragma unroll 8
        for (int d = 0; d < CDIM; ++d) a += c[n * CDIM + d] * cw[co * CDIM + d];
        ctx[idx] = a;
    }
}

// ---------------- main: implicit-GEMM conv, direct-x staging -------------------
// grid: 1024 blocks = 32 n x 32 h-tiles (2 output rows), BN = 256.
// 512 threads = 8 waves (2 m x 4 n); per-wave output 64 pos x 64 co.
// Prologue: zero A_s; read x slab (rows h0-1..h0+2, coalesced 256 B), cvt,
// ds_write_b128 (conflict-free). K-loop: 36 steps (9 taps x 4 kb of 32 ci),
// A from resident LDS, B frags global->VGPR w/ depth-1 prefetch, no barriers.
__global__ __launch_bounds__(512, 4) void conv_mfma(
    const float* __restrict__ x,             // [32][128][64][64]
    const __hip_bfloat16* __restrict__ wT,   // [9][256][128]
    const float* __restrict__ ctx,           // [32][256]
    float* __restrict__ out)                 // [32][256][64][64]
{
    __shared__ __align__(16) short A_s[AROWS * ARSTR];   // 71,808 B

    int bid = blockIdx.x;
    // XCD-bijective swizzle (1024 % 8 == 0)
    int mt  = (bid & 7) * 128 + (bid >> 3);
    int n   = mt >> 5;                    // 0..31
    int h0  = (mt & 31) << 1;             // 2 output h-rows per tile

    int tid  = threadIdx.x;
    int lane = tid & 63, wv = tid >> 6;
    int wm = (wv & 1) * 64;               // wave m-offset (positions)
    int wn = (wv >> 1) * 64;              // wave n-offset (co)
    int l15 = lane & 15, lu = lane >> 4;

    // ---- B fragment base: frag(tap,kb,ni) = 16 contiguous bytes of wT at
    // co = wn + ni*16 + l15, k-octet = kb*4 + lu.
    const __hip_bfloat16* wB = wT + ((size_t)(wn + l15) * CIN) + lu * 8;

    // prefetch B for step 0 (tap 0, kb 0) first — overlaps with LDS fill
    short8 bCur[4], bNxt[4];
    #pragma unroll
    for (int ni = 0; ni < 4; ++ni)
        bCur[ni] = *(const short8*)(wB + (size_t)ni * (16 * CIN));

    // ---- zero A_s (covers halo cols 0,65 and out-of-image h rows)
    #pragma unroll
    for (int z = 0; z < 9; ++z) {
        int g = z * 512 + tid;
        if (g < ACHNK) *(short8*)&A_s[g * 8] = (short8){};
    }
    __syncthreads();

    // ---- fill interior: 64 tasks = 4 h-rows x 16 ci-octets; wave covers 8.
    // lane -> w (0..63): global load of 256 B contiguous per (ci,h) row.
    int h0m1 = h0 - 1;
    #pragma unroll
    for (int i = 0; i < 8; ++i) {
        int task = wv * 8 + i;
        int hl   = task >> 4;                    // padded h index 0..3
        int oct  = task & 15;
        int hh   = h0m1 + hl;
        if (hh >= 0 && hh < HH) {
            const float* src = x + (((size_t)(n * CIN + oct * 8)) * HH + hh) * WW + lane;
            union { short8 s; __hip_bfloat16 b[8]; } u;
            #pragma unroll
            for (int k = 0; k < 8; ++k)
                u.b[k] = __float2bfloat16(src[(size_t)k * HH * WW]);
            int row = hl * 66 + 1 + lane;        // padded col = w+1
            *(short8*)&A_s[row * ARSTR + ((oct) << 3) + 0] = u.s;
        }
    }
    __syncthreads();

    float4v acc[4][4] = {};
    int ohc = wm >> 6;                    // wave's output h-row: 0 or 1

    for (int tap = 0; tap < 9; ++tap) {
        int kh  = (tap * 11) >> 5, kw = tap - kh * 3;
        int rb0 = (ohc + kh) * 66 + l15 + kw;    // A row base
        #pragma unroll
        for (int kb = 0; kb < 4; ++kb) {
            // ---- prefetch B(s+1) (clamped at tail; dead load, harmless)
            int s1 = tap * 4 + kb + 1;
            if (s1 > 35) s1 = 0;
            int tap1 = s1 >> 2, kb1 = s1 & 3;
            const __hip_bfloat16* wNx = wB + (size_t)tap1 * (COUT * CIN) + kb1 * 32;
            #pragma unroll
            for (int ni = 0; ni < 4; ++ni)
                bNxt[ni] = *(const short8*)(wNx + (size_t)ni * (16 * CIN));

            // ---- A fragments (resident LDS, stride-17 padded: no swizzle)
            int cL = kb * 4 + lu;                // chunk 0..15
            short8 aF[4];
            #pragma unroll
            for (int mi = 0; mi < 4; ++mi) {
                int r = rb0 + mi * 16;
                aF[mi] = *(const short8*)&A_s[r * ARSTR + cL * 8];
            }

            // ---- 16 MFMA
            SETPRIO(1);
            #pragma unroll
            for (int mi = 0; mi < 4; ++mi)
                #pragma unroll
                for (int ni = 0; ni < 4; ++ni)
                    acc[mi][ni] = __builtin_amdgcn_mfma_f32_16x16x32_bf16(
                        aF[mi], bCur[ni], acc[mi][ni], 0, 0, 0);
            SETPRIO(0);

            #pragma unroll
            for (int ni = 0; ni < 4; ++ni) bCur[ni] = bNxt[ni];
        }
    }

    // epilogue: += ctx, write float4 (4 consecutive w)
    #pragma unroll
    for (int ni = 0; ni < 4; ++ni) {
        int co = wn + ni * 16 + l15;
        float cv = ctx[n * COUT + co];
        float* ob = out + ((size_t)n * COUT + co) * (HH * WW);
        #pragma unroll
        for (int mi = 0; mi < 4; ++mi) {
            int rp = wm + mi * 16 + (lu << 2);   // row quad base
            int hh = h0 + (rp >> 6);
            int ww = rp & 63;
            float4v v = acc[mi][ni] + cv;
            *(float4v*)&ob[hh * WW + ww] = v;
        }
    }
}

// ---------------- fallback (round-2 verified) ----------------------------------
__global__ __launch_bounds__(256) void contextual_conv_f32(
    const float* __restrict__ x, const float* __restrict__ c,
    const float* __restrict__ wgt, const float* __restrict__ cw,
    const float* __restrict__ bias, float* __restrict__ out)
{
    int idx = blockIdx.x * 256 + threadIdx.x;
    int w = idx & 63, h = (idx >> 6) & 63, cb = (idx >> 12) & 63, n = idx >> 18;
    float acc[4];
    #pragma unroll
    for (int j = 0; j < 4; ++j) acc[j] = bias[cb + j * 64];
    const float* cp = c + n * CDIM;
    for (int d = 0; d < CDIM; ++d) {
        float cv = cp[d];
        #pragma unroll
        for (int j = 0; j < 4; ++j) acc[j] += cv * cw[(cb + j * 64) * CDIM + d];
    }
    const float* xn = x + (size_t)n * (CIN * HH * WW);
    for (int ci = 0; ci < CIN; ++ci) {
        const float* xc = xn + ci * (HH * WW);
        float wv[4][9];
        #pragma unroll
        for (int j = 0; j < 4; ++j) {
            const float* wp = wgt + ((cb + j * 64) * CIN + ci) * 9;
            #pragma unroll
            for (int k = 0; k < 9; ++k) wv[j][k] = wp[k];
        }
        #pragma unroll
        for (int kh = 0; kh < 3; ++kh) {
            int hh = h + kh - 1;
            if (hh < 0 || hh >= HH) continue;
            const float* xr = xc + hh * WW;
            #pragma unroll
            for (int kw = 0; kw < 3; ++kw) {
                int ww = w + kw - 1;
                if (ww < 0 || ww >= WW) continue;
                float xv = xr[ww];
                #pragma unroll
                for (int j = 0; j < 4; ++j) acc[j] += xv * wv[j][kh * 3 + kw];
            }
        }
    }
    size_t obase = (size_t)n * (COUT * HH * WW) + (size_t)h * WW + w;
    #pragma unroll
    for (int j = 0; j < 4; ++j)
        out[obase + (size_t)(cb + j * 64) * (HH * WW)] = acc[j];
}

extern "C" void kernel_launch(void* const* d_in, const int* in_sizes, int n_in,
                              void* d_out, int out_size, void* d_ws, size_t ws_size,
                              hipStream_t stream) {
    const float* x    = (const float*)d_in[0];
    const float* c    = (const float*)d_in[1];
    const float* wgt  = (const float*)d_in[2];
    const float* cw   = (const float*)d_in[3];
    const float* bias = (const float*)d_in[4];
    float* out = (float*)d_out;

    if (ws_size < WS_NEEDED) {   // workspace too small: round-2 fallback
        const int total_threads = NN * 64 * HH * WW;
        contextual_conv_f32<<<total_threads / 256, 256, 0, stream>>>(x, c, wgt, cw, bias, out);
        return;
    }

    char* ws = (char*)d_ws;
    __hip_bfloat16* wT = (__hip_bfloat16*)ws;
    float*          cx = (float*)(ws + WT_BYTES);

    prep_wc  <<<1184, 256, 0, stream>>>(wgt, c, cw, bias, wT, cx);
    conv_mfma<<<1024, 512, 0, stream>>>(x, wT, cx, out);
}

// Round 7
// 262.065 us; speedup vs baseline: 1.2123x; 1.2123x over previous
//
#include <hip/hip_runtime.h>
#include <hip/hip_bf16.h>

// ContextualConv2d as implicit GEMM on MFMA.
// GEMM view: M = N*H*W = 131072, N = C_OUT = 256, K = CIN*9 = 1152.
// Round 11 (resubmit; round 6's bench run died on container infra, no data):
//           r9 geometry (512 blocks x 4 h-rows, 8 waves, acc[8][4]) +
//           direct-x staging (xP deleted, r10-verified prologue+layout) +
//           DEPTH-2 B prefetch in static register slots (bF[2][4], slot=kb&1,
//           fully unrolled): each slot consumed 2 K-steps (~2500 cyc) after
//           issue and reissued right after consumption => compiler waits are
//           effectively vmcnt(4), never a per-step vmcnt(0) drain (r9/r10's
//           serialized ~3300 cyc/step was the depth-1 bCur=bNxt copy).
//           No in-loop barriers, no in-loop setprio (m190: null when free-run).
// A LDS layout (r10-verified): row r (= hl*66 + padded_w) x 17 chunks of 16B
//           (16 data + 1 pad); bank-quad = (17r + c) mod 8 => conflict-free.
// MFMA floor: 4.72e6 MFMA x 19.4 SIMD-cyc / 1024 SIMD = 37 us; target ~60.

#define NN   32
#define CIN  128
#define HH   64
#define WW   64
#define COUT 256
#define CDIM 64

#define WT_BYTES  ((size_t)9*COUT*CIN*2)         //    589,824
#define CTX_BYTES ((size_t)NN*COUT*4)            //     32,768
#define WS_NEEDED (WT_BYTES + CTX_BYTES)

// LDS A: 396 rows (6 padded h x 66 padded w) x 17 chunks (16 data + 1 pad).
#define AROWS 396
#define ARSTR 136                                 // shorts per row (272 B)
#define ACHNK (AROWS*17)                          // 6732 16B chunks

typedef __attribute__((ext_vector_type(8))) short short8;   // 8 bf16 = 4 VGPRs
typedef __attribute__((ext_vector_type(4))) float float4v;

// ---------------- prep_wc: weight transpose + ctx GEMM --------------------------
// blocks 0..1151:  wT[tap][co][ci] = bf16(wgt[co][ci][tap])
// blocks 1152..1183: ctx[n][co] = bias[co] + sum_d c[n,d]*cw[co,d]
__global__ __launch_bounds__(256) void prep_wc(const float* __restrict__ wgt,
                                               const float* __restrict__ c,
                                               const float* __restrict__ cw,
                                               const float* __restrict__ bias,
                                               __hip_bfloat16* __restrict__ wT,
                                               float* __restrict__ ctx) {
    int bid = blockIdx.x;
    if (bid < 1152) {
        int idx = bid * 256 + threadIdx.x;       // 294912
        int ci  = idx & 127;
        int co  = (idx >> 7) & 255;
        int tap = idx >> 15;
        wT[idx] = __float2bfloat16(wgt[((size_t)co * CIN + ci) * 9 + tap]);
    } else {
        int idx = (bid - 1152) * 256 + threadIdx.x;   // 8192
        int co = idx & 255, n = idx >> 8;
        float a = bias[co];
        #pragma unroll 8
        for (int d = 0; d < CDIM; ++d) a += c[n * CDIM + d] * cw[co * CDIM + d];
        ctx[idx] = a;
    }
}

// ---------------- main: implicit-GEMM conv, direct-x, resident-A ---------------
// grid: 512 blocks = 32 n x 16 h-tiles (4 output rows), BN = 256.
// 512 threads = 8 waves (2 m x 4 n); per-wave output 128 pos x 64 co.
// Prologue: zero A_s; fill from x (6 padded rows, transpose+cvt in reg,
// ds_write_b128). K-loop: 36 steps (9 taps x 4 kb), A resident LDS,
// B global->VGPR depth-2 slots, no barriers.
__global__ __launch_bounds__(512, 2) void conv_mfma(
    const float* __restrict__ x,             // [32][128][64][64]
    const __hip_bfloat16* __restrict__ wT,   // [9][256][128]
    const float* __restrict__ ctx,           // [32][256]
    float* __restrict__ out)                 // [32][256][64][64]
{
    __shared__ __align__(16) short A_s[AROWS * ARSTR];   // 107,712 B

    int bid = blockIdx.x;
    // XCD-bijective swizzle (512 % 8 == 0)
    int mt  = (bid & 7) * 64 + (bid >> 3);
    int n   = mt >> 4;                    // 0..31
    int h0  = (mt & 15) << 2;             // 4 output h-rows per tile

    int tid  = threadIdx.x;
    int lane = tid & 63, wv = tid >> 6;
    int wm = (wv & 1) * 128;              // wave m-offset (positions)
    int wn = (wv >> 1) * 64;              // wave n-offset (co)
    int l15 = lane & 15, lu = lane >> 4;

    // ---- B fragment base: frag(tap,kb,ni) = 16 contiguous bytes of wT at
    // co = wn + ni*16 + l15, k-octet = kb*4 + lu.
    const __hip_bfloat16* wB = wT + ((size_t)(wn + l15) * CIN) + lu * 8;

    // depth-2 prefetch: slot parity = kb&1 (tap*4 is even). Load s=0, s=1 now;
    // they land while the LDS fill below is in flight.
    short8 bF[2][4];
    #pragma unroll
    for (int ni = 0; ni < 4; ++ni) {
        bF[0][ni] = *(const short8*)(wB + (size_t)ni * (16 * CIN));          // s=0
        bF[1][ni] = *(const short8*)(wB + (size_t)ni * (16 * CIN) + 32);     // s=1
    }

    // ---- zero A_s (covers halo cols 0,65 and out-of-image h rows)
    #pragma unroll
    for (int z = 0; z < 14; ++z) {
        int g = z * 512 + tid;
        if (g < ACHNK) *(short8*)&A_s[g * 8] = (short8){};
    }
    __syncthreads();

    // ---- fill interior: 96 tasks = 6 padded h-rows x 16 ci-octets; 12/wave.
    // lane -> w (0..63): 8 loads strided HH*WW, cvt, one ds_write_b128.
    int h0m1 = h0 - 1;
    #pragma unroll
    for (int i = 0; i < 12; ++i) {
        int task = wv * 12 + i;
        int hl   = task >> 4;                    // padded h index 0..5
        int oct  = task & 15;
        int hh   = h0m1 + hl;
        if (hh >= 0 && hh < HH) {
            const float* src = x + (((size_t)(n * CIN + oct * 8)) * HH + hh) * WW + lane;
            union { short8 s; __hip_bfloat16 b[8]; } u;
            #pragma unroll
            for (int k = 0; k < 8; ++k)
                u.b[k] = __float2bfloat16(src[(size_t)k * HH * WW]);
            int row = hl * 66 + 1 + lane;        // padded col = w+1
            *(short8*)&A_s[row * ARSTR + (oct << 3)] = u.s;
        }
    }
    __syncthreads();

    float4v acc[8][4] = {};
    int ohc = wm >> 6;                    // wave's output h-row block: 0 or 2

    for (int tap = 0; tap < 9; ++tap) {
        int kh  = (tap * 11) >> 5, kw = tap - kh * 3;
        int rb0 = (ohc + kh) * 66 + l15 + kw;    // A row base
        #pragma unroll
        for (int kb = 0; kb < 4; ++kb) {         // slot = kb&1 (static)
            // ---- A fragments (resident LDS, stride-17 padded layout)
            int cL = kb * 4 + lu;                // chunk 0..15
            short8 aF[8];
            #pragma unroll
            for (int mi = 0; mi < 8; ++mi) {
                int r = rb0 + (mi >> 2) * 66 + (mi & 3) * 16;
                aF[mi] = *(const short8*)&A_s[r * ARSTR + cL * 8];
            }

            // ---- 32 MFMA consuming slot kb&1 (loaded 2 steps ago)
            #pragma unroll
            for (int mi = 0; mi < 8; ++mi)
                #pragma unroll
                for (int ni = 0; ni < 4; ++ni)
                    acc[mi][ni] = __builtin_amdgcn_mfma_f32_16x16x32_bf16(
                        aF[mi], bF[kb & 1][ni], acc[mi][ni], 0, 0, 0);

            // ---- reissue slot kb&1 with step s+2 (WAR: must follow MFMAs)
            int s2 = tap * 4 + kb + 2;
            if (s2 > 35) s2 -= 36;               // tail: dead reload, harmless
            int tap2 = s2 >> 2, kb2 = s2 & 3;
            const __hip_bfloat16* wNx = wB + (size_t)tap2 * (COUT * CIN) + kb2 * 32;
            #pragma unroll
            for (int ni = 0; ni < 4; ++ni)
                bF[kb & 1][ni] = *(const short8*)(wNx + (size_t)ni * (16 * CIN));
        }
    }

    // epilogue: += ctx, write float4 (4 consecutive w)
    #pragma unroll
    for (int ni = 0; ni < 4; ++ni) {
        int co = wn + ni * 16 + l15;
        float cv = ctx[n * COUT + co];
        float* ob = out + ((size_t)n * COUT + co) * (HH * WW);
        #pragma unroll
        for (int mi = 0; mi < 8; ++mi) {
            int rp = wm + mi * 16 + (lu << 2);   // row quad base
            int hh = h0 + (rp >> 6);
            int ww = rp & 63;
            float4v v = acc[mi][ni] + cv;
            *(float4v*)&ob[hh * WW + ww] = v;
        }
    }
}

// ---------------- fallback (round-2 verified) ----------------------------------
__global__ __launch_bounds__(256) void contextual_conv_f32(
    const float* __restrict__ x, const float* __restrict__ c,
    const float* __restrict__ wgt, const float* __restrict__ cw,
    const float* __restrict__ bias, float* __restrict__ out)
{
    int idx = blockIdx.x * 256 + threadIdx.x;
    int w = idx & 63, h = (idx >> 6) & 63, cb = (idx >> 12) & 63, n = idx >> 18;
    float acc[4];
    #pragma unroll
    for (int j = 0; j < 4; ++j) acc[j] = bias[cb + j * 64];
    const float* cp = c + n * CDIM;
    for (int d = 0; d < CDIM; ++d) {
        float cv = cp[d];
        #pragma unroll
        for (int j = 0; j < 4; ++j) acc[j] += cv * cw[(cb + j * 64) * CDIM + d];
    }
    const float* xn = x + (size_t)n * (CIN * HH * WW);
    for (int ci = 0; ci < CIN; ++ci) {
        const float* xc = xn + ci * (HH * WW);
        float wv[4][9];
        #pragma unroll
        for (int j = 0; j < 4; ++j) {
            const float* wp = wgt + ((cb + j * 64) * CIN + ci) * 9;
            #pragma unroll
            for (int k = 0; k < 9; ++k) wv[j][k] = wp[k];
        }
        #pragma unroll
        for (int kh = 0; kh < 3; ++kh) {
            int hh = h + kh - 1;
            if (hh < 0 || hh >= HH) continue;
            const float* xr = xc + hh * WW;
            #pragma unroll
            for (int kw = 0; kw < 3; ++kw) {
                int ww = w + kw - 1;
                if (ww < 0 || ww >= WW) continue;
                float xv = xr[ww];
                #pragma unroll
                for (int j = 0; j < 4; ++j) acc[j] += xv * wv[j][kh * 3 + kw];
            }
        }
    }
    size_t obase = (size_t)n * (COUT * HH * WW) + (size_t)h * WW + w;
    #pragma unroll
    for (int j = 0; j < 4; ++j)
        out[obase + (size_t)(cb + j * 64) * (HH * WW)] = acc[j];
}

extern "C" void kernel_launch(void* const* d_in, const int* in_sizes, int n_in,
                              void* d_out, int out_size, void* d_ws, size_t ws_size,
                              hipStream_t stream) {
    const float* x    = (const float*)d_in[0];
    const float* c    = (const float*)d_in[1];
    const float* wgt  = (const float*)d_in[2];
    const float* cw   = (const float*)d_in[3];
    const float* bias = (const float*)d_in[4];
    float* out = (float*)d_out;

    if (ws_size < WS_NEEDED) {   // workspace too small: round-2 fallback
        const int total_threads = NN * 64 * HH * WW;
        contextual_conv_f32<<<total_threads / 256, 256, 0, stream>>>(x, c, wgt, cw, bias, out);
        return;
    }

    char* ws = (char*)d_ws;
    __hip_bfloat16* wT = (__hip_bfloat16*)ws;
    float*          cx = (float*)(ws + WT_BYTES);

    prep_wc  <<<1184, 256, 0, stream>>>(wgt, c, cw, bias, wT, cx);
    conv_mfma<<<512, 512, 0, stream>>>(x, wT, cx, out);
}